// Round 1
// baseline (3961.622 us; speedup 1.0000x reference)
//
#include <hip/hip_runtime.h>
#include <hip/hip_bf16.h>
#include <cfloat>

// K-means, 16 independent spaces. x: (32768, 16, 64) fp32. Output: (16, 256, 64) fp32.
#define NS 16
#define NPTS 32768
#define DIM 64
#define NC 256
#define NITER 5

constexpr int TPB = 512;                         // threads per assign block
constexpr int CHUNKS = 16;                       // blocks per space
constexpr int PTS_PER_BLOCK = NPTS / CHUNKS;     // 2048
constexpr int PASSES = PTS_PER_BLOCK / TPB;      // 4 points per thread (1 at a time)

// c0[s][k][d] = x[k][s][d]; also c2[s][k] = sum_d c^2
__global__ __launch_bounds__(256) void kminit(const float* __restrict__ x,
                                              float* __restrict__ c,
                                              float* __restrict__ c2) {
  const int tid = threadIdx.x;
  const int g = blockIdx.x * 4 + (tid >> 6);   // (s*NC + k), 4 groups of 64 lanes/block
  const int lane = tid & 63;
  const int s = g >> 8;
  const int k = g & 255;
  float v = x[(size_t)k * (NS * DIM) + s * DIM + lane];
  c[(size_t)g * DIM + lane] = v;
  float sq = v * v;
  #pragma unroll
  for (int off = 32; off; off >>= 1) sq += __shfl_xor(sq, off);
  if (lane == 0) c2[g] = sq;
}

// c = counts>0 ? sums/max(counts,1) : c ; refresh c2
__global__ __launch_bounds__(256) void kmupdate(float* __restrict__ c,
                                                const float* __restrict__ sums,
                                                const float* __restrict__ counts,
                                                float* __restrict__ c2) {
  const int tid = threadIdx.x;
  const int g = blockIdx.x * 4 + (tid >> 6);
  const int lane = tid & 63;
  const float cnt = counts[g];
  const size_t idx = (size_t)g * DIM + lane;
  const float cold = c[idx];
  const float v = (cnt > 0.f) ? (sums[idx] / fmaxf(cnt, 1.f)) : cold;
  c[idx] = v;
  float sq = v * v;
  #pragma unroll
  for (int off = 32; off; off >>= 1) sq += __shfl_xor(sq, off);
  if (lane == 0) c2[g] = sq;
}

// Fused assign + accumulate. One block = one (space, 2048-point chunk).
// x row for the point lives in 64 VGPRs; centroids are wave-uniform -> scalar loads.
// dist = c2[k] - 2*dot(x,c[k])  (x^2 omitted: constant per point, argmin-invariant).
__global__ __launch_bounds__(TPB, 2) void kmassign(const float* __restrict__ x,
                                                   const float* __restrict__ c,
                                                   const float* __restrict__ c2,
                                                   float* __restrict__ sums,
                                                   float* __restrict__ counts) {
  extern __shared__ float ss[];   // [DIM][NC] = 64 KiB; bank(k,d) = k%32 -> lanes spread
  const int tid = threadIdx.x;
  const int bx = blockIdx.x;
  const int s = bx & (NS - 1);
  const int chunk = bx >> 4;

  for (int i = tid; i < DIM * NC; i += TPB) ss[i] = 0.f;
  __syncthreads();

  const float* __restrict__ cb = c + (size_t)s * NC * DIM;    // block-uniform
  const float* __restrict__ c2b = c2 + s * NC;                // block-uniform

  for (int pass = 0; pass < PASSES; ++pass) {
    const int prow = chunk * PTS_PER_BLOCK + pass * TPB + tid;
    const float4* __restrict__ xr =
        (const float4*)(x + (size_t)prow * (NS * DIM) + s * DIM);
    float xv[DIM];
    #pragma unroll
    for (int j = 0; j < DIM / 4; ++j) {
      float4 t = xr[j];
      xv[4 * j + 0] = t.x; xv[4 * j + 1] = t.y;
      xv[4 * j + 2] = t.z; xv[4 * j + 3] = t.w;
    }

    float bestd = FLT_MAX;
    int bi = 0;
    #pragma unroll 2
    for (int k0 = 0; k0 < NC; k0 += 4) {
      float a0 = 0.f, a1 = 0.f, a2 = 0.f, a3 = 0.f;
      #pragma unroll
      for (int d = 0; d < DIM; ++d) {
        const float xd = xv[d];
        a0 = fmaf(cb[(k0 + 0) * DIM + d], xd, a0);
        a1 = fmaf(cb[(k0 + 1) * DIM + d], xd, a1);
        a2 = fmaf(cb[(k0 + 2) * DIM + d], xd, a2);
        a3 = fmaf(cb[(k0 + 3) * DIM + d], xd, a3);
      }
      const float d0 = fmaf(-2.f, a0, c2b[k0 + 0]);
      const float d1 = fmaf(-2.f, a1, c2b[k0 + 1]);
      const float d2 = fmaf(-2.f, a2, c2b[k0 + 2]);
      const float d3 = fmaf(-2.f, a3, c2b[k0 + 3]);
      // ascending k + strict < == jnp.argmin first-min tie-break
      if (d0 < bestd) { bestd = d0; bi = k0 + 0; }
      if (d1 < bestd) { bestd = d1; bi = k0 + 1; }
      if (d2 < bestd) { bestd = d2; bi = k0 + 2; }
      if (d3 < bestd) { bestd = d3; bi = k0 + 3; }
    }

    unsafeAtomicAdd(&counts[s * NC + bi], 1.0f);
    #pragma unroll
    for (int d = 0; d < DIM; ++d) atomicAdd(&ss[d * NC + bi], xv[d]);
  }

  __syncthreads();
  float* __restrict__ sb = sums + (size_t)s * NC * DIM;
  for (int i = tid; i < DIM * NC; i += TPB) {
    const int d = i >> 8;
    const int k = i & 255;
    unsafeAtomicAdd(&sb[k * DIM + d], ss[i]);
  }
}

extern "C" void kernel_launch(void* const* d_in, const int* in_sizes, int n_in,
                              void* d_out, int out_size, void* d_ws, size_t ws_size,
                              hipStream_t stream) {
  const float* x = (const float*)d_in[0];
  float* c = (float*)d_out;                      // centroids live in d_out
  float* sums = (float*)d_ws;                    // [NS][NC][DIM]
  float* counts = sums + (size_t)NS * NC * DIM;  // [NS][NC]
  float* c2 = counts + NS * NC;                  // [NS][NC]

  kminit<<<NS * NC / 4, 256, 0, stream>>>(x, c, c2);
  for (int it = 0; it < NITER; ++it) {
    hipMemsetAsync(d_ws, 0, (size_t)(NS * NC * DIM + NS * NC) * sizeof(float), stream);
    kmassign<<<NS * CHUNKS, TPB, DIM * NC * sizeof(float), stream>>>(x, c, c2, sums, counts);
    kmupdate<<<NS * NC / 4, 256, 0, stream>>>(c, sums, counts, c2);
  }
}

// Round 4
// 3811.848 us; speedup vs baseline: 1.0393x; 1.0393x over previous
//
#include <hip/hip_runtime.h>
#include <hip/hip_bf16.h>
#include <cfloat>

// K-means, 16 independent spaces. x: (32768, 16, 64) fp32. Output: (16, 256, 64) fp32.
#define NS 16
#define NPTS 32768
#define DIM 64
#define NC 256
#define NITER 5

constexpr int TPB = 512;                         // threads per assign block
constexpr int CHUNKS = 16;                       // blocks per space (256 blocks = 1/CU)
constexpr int PTS_PER_BLOCK = NPTS / CHUNKS;     // 2048
constexpr int PASSES = PTS_PER_BLOCK / TPB;      // 4 points per thread (1 at a time)

// c0[s][k][d] = x[k][s][d]; also c2[s][k] = sum_d c^2
__global__ __launch_bounds__(256) void kminit(const float* __restrict__ x,
                                              float* __restrict__ c,
                                              float* __restrict__ c2) {
  const int tid = threadIdx.x;
  const int g = blockIdx.x * 4 + (tid >> 6);   // (s*NC + k), 4 groups of 64 lanes/block
  const int lane = tid & 63;
  const int s = g >> 8;
  const int k = g & 255;
  float v = x[(size_t)k * (NS * DIM) + s * DIM + lane];
  c[(size_t)g * DIM + lane] = v;
  float sq = v * v;
  #pragma unroll
  for (int off = 32; off; off >>= 1) sq += __shfl_xor(sq, off);
  if (lane == 0) c2[g] = sq;
}

// c = counts>0 ? sums/max(counts,1) : c ; refresh c2
__global__ __launch_bounds__(256) void kmupdate(float* __restrict__ c,
                                                const float* __restrict__ sums,
                                                const float* __restrict__ counts,
                                                float* __restrict__ c2) {
  const int tid = threadIdx.x;
  const int g = blockIdx.x * 4 + (tid >> 6);
  const int lane = tid & 63;
  const float cnt = counts[g];
  const size_t idx = (size_t)g * DIM + lane;
  const float cold = c[idx];
  const float v = (cnt > 0.f) ? (sums[idx] / fmaxf(cnt, 1.f)) : cold;
  c[idx] = v;
  float sq = v * v;
  #pragma unroll
  for (int off = 32; off; off >>= 1) sq += __shfl_xor(sq, off);
  if (lane == 0) c2[g] = sq;
}

// Fused assign + accumulate. One block = one (space, 2048-point chunk).
// x row for the point lives in 64 VGPRs; centroids are wave-uniform -> s_load/SGPR
// (confirmed R1: SGPR_Count=112). dist = c2[k] - 2*dot(x,c[k]); x^2 dropped
// (constant per point, argmin-invariant).
//
// amdgpu_waves_per_eu(2,2): R1 spilled xv[64] to scratch (VGPR_Count=44,
// 134 MB scratch stores) because the allocator targeted 8 waves/EU the
// 256-block grid can't use. Pin the target at 2 waves/EU -> 256-VGPR budget.
__global__ __launch_bounds__(TPB)
__attribute__((amdgpu_waves_per_eu(2, 2)))
void kmassign(const float* __restrict__ x,
              const float* __restrict__ c,
              const float* __restrict__ c2,
              float* __restrict__ sums,
              float* __restrict__ counts) {
  __shared__ float ss[DIM * NC];    // [DIM][NC] = 64 KiB; bank(k,d) = k%32
  __shared__ float scnt[NC];        // per-block counts (was global atomics in R1)
  const int tid = threadIdx.x;
  const int bx = blockIdx.x;
  const int s = bx & (NS - 1);
  const int chunk = bx >> 4;

  for (int i = tid; i < DIM * NC; i += TPB) ss[i] = 0.f;
  if (tid < NC) scnt[tid] = 0.f;
  __syncthreads();

  const float* __restrict__ cb = c + (size_t)s * NC * DIM;    // block-uniform
  const float* __restrict__ c2b = c2 + s * NC;                // block-uniform

  for (int pass = 0; pass < PASSES; ++pass) {
    const int prow = chunk * PTS_PER_BLOCK + pass * TPB + tid;
    const float4* __restrict__ xr =
        (const float4*)(x + (size_t)prow * (NS * DIM) + s * DIM);
    float xv[DIM];
    #pragma unroll
    for (int j = 0; j < DIM / 4; ++j) {
      float4 t = xr[j];
      xv[4 * j + 0] = t.x; xv[4 * j + 1] = t.y;
      xv[4 * j + 2] = t.z; xv[4 * j + 3] = t.w;
    }

    float bestd = FLT_MAX;
    int bi = 0;
    for (int k0 = 0; k0 < NC; k0 += 4) {
      float a0 = 0.f, a1 = 0.f, a2 = 0.f, a3 = 0.f;
      #pragma unroll
      for (int d = 0; d < DIM; ++d) {
        const float xd = xv[d];
        a0 = fmaf(cb[(k0 + 0) * DIM + d], xd, a0);
        a1 = fmaf(cb[(k0 + 1) * DIM + d], xd, a1);
        a2 = fmaf(cb[(k0 + 2) * DIM + d], xd, a2);
        a3 = fmaf(cb[(k0 + 3) * DIM + d], xd, a3);
      }
      const float d0 = fmaf(-2.f, a0, c2b[k0 + 0]);
      const float d1 = fmaf(-2.f, a1, c2b[k0 + 1]);
      const float d2 = fmaf(-2.f, a2, c2b[k0 + 2]);
      const float d3 = fmaf(-2.f, a3, c2b[k0 + 3]);
      // ascending k + strict < == jnp.argmin first-min tie-break
      if (d0 < bestd) { bestd = d0; bi = k0 + 0; }
      if (d1 < bestd) { bestd = d1; bi = k0 + 1; }
      if (d2 < bestd) { bestd = d2; bi = k0 + 2; }
      if (d3 < bestd) { bestd = d3; bi = k0 + 3; }
    }

    atomicAdd(&scnt[bi], 1.0f);
    #pragma unroll
    for (int d = 0; d < DIM; ++d) atomicAdd(&ss[d * NC + bi], xv[d]);
  }

  __syncthreads();
  float* __restrict__ sb = sums + (size_t)s * NC * DIM;
  for (int i = tid; i < DIM * NC; i += TPB) {
    const int d = i >> 8;
    const int k = i & 255;
    unsafeAtomicAdd(&sb[k * DIM + d], ss[i]);
  }
  if (tid < NC) unsafeAtomicAdd(&counts[s * NC + tid], scnt[tid]);
}

extern "C" void kernel_launch(void* const* d_in, const int* in_sizes, int n_in,
                              void* d_out, int out_size, void* d_ws, size_t ws_size,
                              hipStream_t stream) {
  const float* x = (const float*)d_in[0];
  float* c = (float*)d_out;                      // centroids live in d_out
  float* sums = (float*)d_ws;                    // [NS][NC][DIM]
  float* counts = sums + (size_t)NS * NC * DIM;  // [NS][NC]
  float* c2 = counts + NS * NC;                  // [NS][NC]

  kminit<<<NS * NC / 4, 256, 0, stream>>>(x, c, c2);
  for (int it = 0; it < NITER; ++it) {
    hipMemsetAsync(d_ws, 0, (size_t)(NS * NC * DIM + NS * NC) * sizeof(float), stream);
    kmassign<<<NS * CHUNKS, TPB, 0, stream>>>(x, c, c2, sums, counts);
    kmupdate<<<NS * NC / 4, 256, 0, stream>>>(c, sums, counts, c2);
  }
}